// Round 1
// baseline (69.194 us; speedup 1.0000x reference)
//
#include <hip/hip_runtime.h>
#include <math.h>

#define TS 64
#define T 64
#define K 256
#define NSEG 4
#define KSEG 64
#define IMG_W 512

// Single fused kernel: 512 blocks x 512 threads, 2 blocks/CU.
//
// Stage (tid<256): gather gaussian tid of this block's tile, build LDS
// records + conservative cull radius:
//   alpha_raw = op*exp(-0.5*maha) = exp2(ea*dx^2 + eb*dx*dy + ed*dy^2 + lop)
//   s = -0.5*log2(e)/det: ea=s*d, eb=-s*(b+c), ed=s*a, lop=log2(op)
//   r^2 = 2*ln(op/0.01)*(a+d): beyond it maha >= d2/(a+d) forces
//   op*exp(-maha/2) <= 0.01 -> clip == 0.01f bit-exactly.
// Dual prefix scan (threads 0-255: col; 256-511: k*col) -> sPA/sPK, enabling
// O(1) compositing of a "far run" [i,j) where every alpha == 0.01:
//   local trans is affine in k:
//   dC = 0.01*[(1-S)*P1 - 0.01*(Pk - i*P1)],  dS = 0.01*len.
//
// Render: seg = tid>>7 handles k in [seg*64, seg*64+64); wave = 64 cols x
// 4-row band; its 64-bit near-mask comes from one __ballot (lane l tests
// gaussian kb+l vs the band rect). ~1-3 near gaussians get full math; far
// stretches collapse to runs.
// Segment combine: C = C_0 + sum_{s>=1}(C_s - S_prev(s)*A_s).
__global__ __launch_bounds__(512, 4) void render_all(
    const float* __restrict__ mu, const float* __restrict__ cov,
    const float* __restrict__ opacity, const float* __restrict__ color,
    const int* __restrict__ tile_idx, float* __restrict__ out) {
  __shared__ float4 sA[K];     // mux, muy, ea, eb
  __shared__ float4 sB[K];     // ed, lop, cr, cg
  __shared__ float sC[K];      // cb
  __shared__ float sR[K];      // r2
  __shared__ float4 sbuf[2 * K];  // scan working: [0,256)=col, [256,512)=k*col
  __shared__ float4 sPA[K + 1];
  __shared__ float4 sPK[K + 1];
  __shared__ float sS[NSEG][128][4];
  __shared__ float sD[3][128][4][3];

  int tid = threadIdx.x;
  int blk = blockIdx.x;
  int tile = blk & 63;   // XCD affinity: tile%8 == blk%8
  int chunk = blk >> 6;  // 0..7

  if (tid < K) {
    int n = tile_idx[tile * K + tid];
    float a = cov[4 * n + 0];
    float b = cov[4 * n + 1];
    float c = cov[4 * n + 2];
    float d = cov[4 * n + 3];
    float det = fmaxf(a * d - b * c, 1e-6f);
    const float LOG2E = 1.4426950408889634f;
    float s = -0.5f * LOG2E / det;
    float mx = mu[2 * n], my = mu[2 * n + 1];
    float lop = log2f(fmaxf(opacity[n], 1e-30f));
    float cr = color[3 * n], cg = color[3 * n + 1], cb = color[3 * n + 2];
    sA[tid] = make_float4(mx, my, s * d, -s * (b + c));
    sB[tid] = make_float4(s * a, lop, cr, cg);
    sC[tid] = cb;
    float r2 = 1.3862943611f * (lop + 6.6438561898f) * (a + d);
    sR[tid] = r2 * 1.0001f + 1e-3f;
    sbuf[tid] = make_float4(cr, cg, cb, 0.f);
    float fk = (float)tid;
    sbuf[K + tid] = make_float4(fk * cr, fk * cg, fk * cb, 0.f);
  }
  __syncthreads();

  // Dual Hillis-Steele scan: lower half of block scans col, upper scans k*col.
  int lane256 = tid & 255;
  float4* mybuf = sbuf + (tid & 256);
  for (int off = 1; off < K; off <<= 1) {
    float4 t;
    bool act = lane256 >= off;
    if (act) t = mybuf[lane256 - off];
    __syncthreads();
    if (act) {
      float4 u = mybuf[lane256];
      mybuf[lane256] = make_float4(u.x + t.x, u.y + t.y, u.z + t.z, 0.f);
    }
    __syncthreads();
  }
  if (tid < K) {
    sPA[tid + 1] = sbuf[tid];
  } else {
    sPK[lane256 + 1] = sbuf[K + lane256];
  }
  if (tid == 0) {
    sPA[0] = make_float4(0.f, 0.f, 0.f, 0.f);
    sPK[0] = make_float4(0.f, 0.f, 0.f, 0.f);
  }
  __syncthreads();

  int seg = __builtin_amdgcn_readfirstlane(tid >> 7);  // 0..3, wave-uniform
  int pslot = tid & 127;
  int lx = pslot & 63;
  int bnd = __builtin_amdgcn_readfirstlane(chunk * 2 + ((tid >> 6) & 1));
  int ty = tile >> 3, tx = tile & 7;
  int ly0 = bnd * 4;
  float px = (float)(tx * TS + lx) + 0.5f;
  float py0 = (float)(ty * TS + ly0) + 0.5f;
  const int kb = seg * KSEG;

  // Near-mask for this wave's (seg, band): lane l tests gaussian kb+l.
  unsigned long long m;
  {
    int l = tid & 63;
    float4 Ag = sA[kb + l];
    float r2 = sR[kb + l];
    float x0 = tx * TS + 0.5f, x1 = tx * TS + 63.5f;
    float y0 = py0, y1 = py0 + 3.0f;
    float dxm = fmaxf(fmaxf(Ag.x - x1, x0 - Ag.x), 0.f);
    float dym = fmaxf(fmaxf(Ag.y - y1, y0 - Ag.y), 0.f);
    float d2 = fmaf(dxm, dxm, dym * dym);
    m = __ballot(d2 < r2);
  }

  float C[4][3] = {};
  float An[4][3] = {};
  float Af[3] = {0.f, 0.f, 0.f};
  float S[4] = {};

  int i = kb;
  while (true) {
    int j = (m != 0ULL) ? (kb + (int)__builtin_ctzll(m)) : (kb + KSEG);
    if (j > i) {  // far run [i, j): every alpha == 0.01 exactly
      float len = (float)(j - i);
      float4 paj = sPA[j], pai = sPA[i];
      float4 pkj = sPK[j], pki = sPK[i];
      float P1r = paj.x - pai.x, P1g = paj.y - pai.y, P1b = paj.z - pai.z;
      float fi = (float)i;
      float Rr = -1e-4f * fmaf(-fi, P1r, pkj.x - pki.x);
      float Rg = -1e-4f * fmaf(-fi, P1g, pkj.y - pki.y);
      float Rb = -1e-4f * fmaf(-fi, P1b, pkj.z - pki.z);
      Af[0] = fmaf(0.01f, P1r, Af[0]);
      Af[1] = fmaf(0.01f, P1g, Af[1]);
      Af[2] = fmaf(0.01f, P1b, Af[2]);
#pragma unroll
      for (int p = 0; p < 4; ++p) {
        float t = fmaf(-0.01f, S[p], 0.01f);  // 0.01*(1 - S_local)
        C[p][0] = fmaf(t, P1r, C[p][0]) + Rr;
        C[p][1] = fmaf(t, P1g, C[p][1]) + Rg;
        C[p][2] = fmaf(t, P1b, C[p][2]) + Rb;
        S[p] = fmaf(0.01f, len, S[p]);
      }
    }
    if (j >= kb + KSEG) break;
    // near gaussian k = j: full math
    float4 A4 = sA[j];
    float4 B4 = sB[j];
    float cbv = sC[j];
    float dx = px - A4.x;
    float tb = A4.w * dx;
    float base = fmaf(A4.z * dx, dx, B4.y);
    float dy = py0 - A4.y;
#pragma unroll
    for (int p = 0; p < 4; ++p) {
      float dyp = dy + (float)p;
      float mm = fmaf(dyp, fmaf(B4.x, dyp, tb), base);
      float al =
          __builtin_amdgcn_fmed3f(__builtin_amdgcn_exp2f(mm), 0.01f, 0.99f);
      float w = fmaf(-al, S[p], al);
      C[p][0] = fmaf(w, B4.z, C[p][0]);
      C[p][1] = fmaf(w, B4.w, C[p][1]);
      C[p][2] = fmaf(w, cbv, C[p][2]);
      An[p][0] = fmaf(al, B4.z, An[p][0]);
      An[p][1] = fmaf(al, B4.w, An[p][1]);
      An[p][2] = fmaf(al, cbv, An[p][2]);
      S[p] += al;
    }
    m &= (m - 1ULL);
    i = j + 1;
  }

#pragma unroll
  for (int p = 0; p < 4; ++p) sS[seg][pslot][p] = S[p];
  __syncthreads();

  if (seg >= 1) {
#pragma unroll
    for (int p = 0; p < 4; ++p) {
      float Sp = sS[0][pslot][p];
      if (seg >= 2) Sp += sS[1][pslot][p];
      if (seg >= 3) Sp += sS[2][pslot][p];
      sD[seg - 1][pslot][p][0] = fmaf(-Sp, An[p][0] + Af[0], C[p][0]);
      sD[seg - 1][pslot][p][1] = fmaf(-Sp, An[p][1] + Af[1], C[p][1]);
      sD[seg - 1][pslot][p][2] = fmaf(-Sp, An[p][2] + Af[2], C[p][2]);
    }
  }
  __syncthreads();

  if (seg == 0) {
    int x = tx * TS + lx;
#pragma unroll
    for (int p = 0; p < 4; ++p) {
      int y = ty * TS + ly0 + p;
      size_t o = ((size_t)y * IMG_W + x) * 3;
      out[o + 0] = C[p][0] + sD[0][pslot][p][0] + sD[1][pslot][p][0] +
                   sD[2][pslot][p][0];
      out[o + 1] = C[p][1] + sD[0][pslot][p][1] + sD[1][pslot][p][1] +
                   sD[2][pslot][p][1];
      out[o + 2] = C[p][2] + sD[0][pslot][p][2] + sD[1][pslot][p][2] +
                   sD[2][pslot][p][2];
    }
  }
}

extern "C" void kernel_launch(void* const* d_in, const int* in_sizes, int n_in,
                              void* d_out, int out_size, void* d_ws,
                              size_t ws_size, hipStream_t stream) {
  const float* mu = (const float*)d_in[0];
  const float* cov = (const float*)d_in[1];
  const float* opacity = (const float*)d_in[2];
  const float* color = (const float*)d_in[3];
  const int* tile_idx = (const int*)d_in[4];
  float* out = (float*)d_out;
  (void)d_ws;
  (void)ws_size;

  render_all<<<T * 8, 512, 0, stream>>>(mu, cov, opacity, color, tile_idx,
                                        out);
}